// Round 13
// baseline (261.370 us; speedup 1.0000x reference)
//
#include <hip/hip_runtime.h>

// VoxelHashTableFlowTraverse: 8-corner hash-grid lookup + trilinear blend.
// R13: latency-hiding restructure (R12 proved blend-LDS BW is not binding;
// the main kernel is phase-serialization bound at 4 blocks/CU):
//  - 2x2x2-voxel bins (131072): neighborhood 27 rows = 13KB LDS, 256-thread
//    blocks -> 8 blocks/CU, 2x the independent stage/blend pipelines;
//  - compact active-bin list (~36k bins) + persistent 2048-block main grid:
//    empty bins never dispatch;
//  - keeps R10's proven parts: XCD-local bin atomics, pre-divided grid
//    coords, f32 rows with conflict-free 480B-stride access, 16-lane blend.

#define TABLE_MASK ((1u << 20) - 1u)
#define FEAT_DIM 120
#define ROW_STRIDE 120            // floats per row (480B; verified 0-conflict)
#define NROWS 27                  // 3 x 3 x 3 neighborhood rows
#define NCHUNK 30                 // 120 floats = 30 float4 per row
#define NXCD 8
#define C8 12                     // per-XCD per-bin capacity (mean ~3.5)

// Bins: 2x2x2 voxels -> 64 x 128 x 16 = 131072 bins.
#define NBINS_X 64
#define NBINS_Y 128
#define NBINS_Z 16
#define NBINS (NBINS_X * NBINS_Y * NBINS_Z)

typedef float f4 __attribute__((ext_vector_type(4)));

__global__ __launch_bounds__(256) void zero_kernel(int* __restrict__ hist8) {
    const int i = blockIdx.x * blockDim.x + threadIdx.x;
    if (i < NXCD * NBINS + 2) hist8[i] = 0;  // +0: ovf count, +1: active count
}

// Single-pass binning with XCD-local counters (RMW at the issuing XCD's L2).
// Stores pre-divided grid coords {gx,gy,gz,bits(q)}.
__global__ __launch_bounds__(256) void bin_kernel(
    const float* __restrict__ qp, int* __restrict__ hist8,
    f4* __restrict__ sq8, f4* __restrict__ ovf, int Cr, int M)
{
    const int q = blockIdx.x * blockDim.x + threadIdx.x;
    if (q >= M) return;

    int xcd;
    asm volatile("s_getreg_b32 %0, hwreg(HW_REG_XCC_ID)" : "=s"(xcd));
    xcd &= (NXCD - 1);

    // Divide by 0.1f (not *10) to match reference rounding.
    const float gx = qp[3 * q + 0] / 0.1f;
    const float gy = qp[3 * q + 1] / 0.1f;
    const float gz = qp[3 * q + 2] / 0.1f;
    const int bx = (int)floorf(gx);
    const int by = (int)floorf(gy);
    const int bz = (int)floorf(gz);
    const int kx = ((bx + 32) >> 1) & (NBINS_X - 1);
    const int ky = ((by + 96) >> 1) & (NBINS_Y - 1);
    const int kz = (bz >> 1) & (NBINS_Z - 1);
    const int key = ((kx * NBINS_Y) + ky) * NBINS_Z + kz;

    const int pos = __hip_atomic_fetch_add(&hist8[xcd * NBINS + key], 1,
                                           __ATOMIC_RELAXED,
                                           __HIP_MEMORY_SCOPE_WORKGROUP);
    f4 s;
    s.x = gx; s.y = gy; s.z = gz; s.w = __int_as_float(q);
    if (pos < Cr) {
        sq8[((size_t)xcd * NBINS + key) * C8 + pos] = s;
    } else {
        const int o = atomicAdd(&hist8[NXCD * NBINS], 1);   // device scope, rare
        if (o < M) ovf[o] = s;
    }
}

// Compact: append bins with any queries to the active list.
__global__ __launch_bounds__(256) void compact_kernel(
    const int* __restrict__ hist8, int* __restrict__ nact,
    int* __restrict__ list)
{
    const int i = blockIdx.x * blockDim.x + threadIdx.x;
    if (i >= NBINS) return;
    int tot = 0;
#pragma unroll
    for (int s = 0; s < NXCD; ++s) tot += hist8[s * NBINS + i];
    if (tot > 0) {
        const int p = atomicAdd(nact, 1);
        list[p] = i;
    }
}

// Main: persistent blocks grid-stride the active-bin list.
__global__ __launch_bounds__(256, 8) void voxel_trilinear_kernel(
    const f4*    __restrict__ sq8,     // [NXCD][NBINS][C8] padded bin slots
    const float* __restrict__ feat,    // [n_vox,120]
    const int*   __restrict__ table,   // [2^20]
    const int*   __restrict__ hist8,   // [NXCD][NBINS] bin counts
    const int*   __restrict__ nactp,   // active count
    const int*   __restrict__ list,    // active bin ids
    float*       __restrict__ out,     // [M,120]
    int Cr)
{
    __shared__ int   cnt_s[NXCD];
    __shared__ int   pre_s[NXCD + 1];
    __shared__ int   vox[NROWS];
    __shared__ f4    sqL[NXCD * C8];                        // 1.5 KB
    __shared__ float rows[NROWS * ROW_STRIDE];              // 12.96 KB

    const int t = threadIdx.x;
    const int nact = *nactp;

    for (int bi = blockIdx.x; bi < nact; bi += gridDim.x) {
        const int wg = list[bi];
        __syncthreads();                 // LDS reuse guard across iterations

        // S1: per-XCD counts.
        if (t < NXCD) {
            int c = hist8[t * NBINS + wg];
            cnt_s[t] = (c > Cr) ? Cr : c;    // overflow handled by ovf_kernel
        }
        __syncthreads();
        if (t == 0) {
            int acc = 0;
            pre_s[0] = 0;
#pragma unroll
            for (int i = 0; i < NXCD; ++i) { acc += cnt_s[i]; pre_s[i + 1] = acc; }
        }
        __syncthreads();
        const int total = pre_s[NXCD];

        const int binx = wg >> 11;           // / (128*16)
        const int biny = (wg >> 4) & 127;
        const int binz = wg & 15;
        const int vx0 = binx * 2 - 32;
        const int vy0 = biny * 2 - 96;
        const int vz0 = binz * 2;

        // S2: probe hash table (t<27); load queries into LDS (t>=128).
        if (t < NROWS) {
            const int i = t / 9;             // x offset 0..2
            const int j = (t / 3) % 3;       // y offset 0..2
            const int k = t % 3;             // z offset 0..2
            const unsigned h = (unsigned)(vx0 + i) * 73856093u
                             + (unsigned)(vy0 + j) * 19349669u
                             + (unsigned)(vz0 + k) * 83492791u;
            vox[t] = table[h & TABLE_MASK];
        }
        if (t >= 128) {
            const int seg = (t - 128) >> 4;  // 8 segments of 16 threads
            const int lane16 = t & 15;
            if (lane16 < cnt_s[seg])
                sqL[pre_s[seg] + lane16] =
                    sq8[((size_t)seg * NBINS + wg) * C8 + lane16];
        }
        __syncthreads();

        // S3: stage rows (f32, zero-fill empty slots -> maskless blend).
        for (int idx = t; idx < NROWS * NCHUNK; idx += 256) {
            const int row = idx / NCHUNK;
            const int chunk = idx - row * NCHUNK;
            const int v = vox[row];
            f4 val = (f4)(0.0f);
            if (v >= 0)
                val = *reinterpret_cast<const f4*>(
                    feat + (size_t)v * FEAT_DIM + chunk * 4);
            *reinterpret_cast<f4*>(rows + row * ROW_STRIDE + chunk * 4) = val;
        }
        __syncthreads();

        // S4: blend. 16 lanes per query, 16 query-groups per block.
        const int group = t >> 4;
        const int l = t & 15;
        const int CX[8] = {0, 1, 0, 0, 1, 1, 0, 1};
        const int CY[8] = {0, 0, 1, 0, 1, 0, 1, 1};
        const int CZ[8] = {0, 0, 0, 1, 0, 1, 1, 1};

        for (int qs = group; qs < total; qs += 16) {
            const f4 qv = sqL[qs];
            const float rx = qv.x - floorf(qv.x);
            const float ry = qv.y - floorf(qv.y);
            const float rz = qv.z - floorf(qv.z);
            const int q = __float_as_int(qv.w);
            const int lx = ((int)floorf(qv.x) + 32) & 1;
            const int ly = ((int)floorf(qv.y) + 96) & 1;
            const int lz = (int)floorf(qv.z) & 1;

            const float sx = 1.0f - rx, sy = 1.0f - ry, sz = 1.0f - rz;
            // Corner order matches reference.
            float w[8];
            w[0] = sx * sy * sz;
            w[1] = rx * sy * sz;
            w[2] = sx * ry * sz;
            w[3] = sx * sy * rz;
            w[4] = rx * ry * sz;
            w[5] = rx * sy * rz;
            w[6] = sx * ry * rz;
            w[7] = rx * ry * rz;

            // Lane l accumulates float4 chunks l and l+14 of the row.
            f4 a0 = (f4)(0.0f), a1 = (f4)(0.0f);
#pragma unroll
            for (int k = 0; k < 8; ++k) {
                const int row = ((lx + CX[k]) * 3 + (ly + CY[k])) * 3 + (lz + CZ[k]);
                const float* rp = rows + row * ROW_STRIDE;
                const f4 fa = *reinterpret_cast<const f4*>(rp + l * 4);
                const f4 fb = *reinterpret_cast<const f4*>(rp + 56 + l * 4);
                a0 += fa * w[k];
                a1 += fb * w[k];
            }

            float* po = out + (size_t)q * FEAT_DIM;
            __builtin_nontemporal_store(a0, reinterpret_cast<f4*>(po + l * 4));
            if (l >= 2)
                __builtin_nontemporal_store(a1, reinterpret_cast<f4*>(po + 56 + l * 4));
        }
    }
}

// Overflow fixup: direct 16-lane gather per query (normally ~zero work).
__global__ __launch_bounds__(256) void ovf_kernel(
    const f4*    __restrict__ ovf,
    const int*   __restrict__ hist8,   // hist8[NXCD*NBINS] = ovf count
    const float* __restrict__ feat,
    const int*   __restrict__ table,
    float*       __restrict__ out,
    int M)
{
    int n = hist8[NXCD * NBINS];
    if (n > M) n = M;
    if (n == 0) return;

    const int nthreads = gridDim.x * 256;
    for (int i = blockIdx.x * 256 + threadIdx.x; i < n * 16; i += nthreads) {
        const int g = i >> 4;
        const int l = i & 15;
        const f4 qv = ovf[g];
        const float gx = qv.x, gy = qv.y, gz = qv.z;
        const int q = __float_as_int(qv.w);
        const float flx = floorf(gx), fly = floorf(gy), flz = floorf(gz);
        const float rx = gx - flx, ry = gy - fly, rz = gz - flz;
        const int bx = (int)flx, by = (int)fly, bz = (int)flz;

        const unsigned hx0 = (unsigned)bx * 73856093u;
        const unsigned hy0 = (unsigned)by * 19349669u;
        const unsigned hz0 = (unsigned)bz * 83492791u;
        const unsigned hx1 = hx0 + 73856093u;
        const unsigned hy1 = hy0 + 19349669u;
        const unsigned hz1 = hz0 + 83492791u;

        unsigned h[8];
        h[0] = (hx0 + hy0 + hz0) & TABLE_MASK;
        h[1] = (hx1 + hy0 + hz0) & TABLE_MASK;
        h[2] = (hx0 + hy1 + hz0) & TABLE_MASK;
        h[3] = (hx0 + hy0 + hz1) & TABLE_MASK;
        h[4] = (hx1 + hy1 + hz0) & TABLE_MASK;
        h[5] = (hx1 + hy0 + hz1) & TABLE_MASK;
        h[6] = (hx0 + hy1 + hz1) & TABLE_MASK;
        h[7] = (hx1 + hy1 + hz1) & TABLE_MASK;

        int vidx[8];
#pragma unroll
        for (int k = 0; k < 8; ++k) vidx[k] = table[h[k]];

        const float sxw = 1.0f - rx, syw = 1.0f - ry, szw = 1.0f - rz;
        float w[8];
        w[0] = sxw * syw * szw;
        w[1] = rx  * syw * szw;
        w[2] = sxw * ry  * szw;
        w[3] = sxw * syw * rz;
        w[4] = rx  * ry  * szw;
        w[5] = rx  * syw * rz;
        w[6] = sxw * ry  * rz;
        w[7] = rx  * ry  * rz;

        f4 a0 = (f4)(0.0f), a1 = (f4)(0.0f);
#pragma unroll
        for (int k = 0; k < 8; ++k) {
            const int v = vidx[k] >= 0 ? vidx[k] : 0;
            const float wk = vidx[k] >= 0 ? w[k] : 0.0f;
            const float* rp = feat + (size_t)v * FEAT_DIM;
            const f4 fa = *reinterpret_cast<const f4*>(rp + l * 4);
            const f4 fb = *reinterpret_cast<const f4*>(rp + 56 + l * 4);
            a0 += fa * wk;
            a1 += fb * wk;
        }

        float* po = out + (size_t)q * FEAT_DIM;
        __builtin_nontemporal_store(a0, reinterpret_cast<f4*>(po + l * 4));
        if (l >= 2)
            __builtin_nontemporal_store(a1, reinterpret_cast<f4*>(po + 56 + l * 4));
    }
}

extern "C" void kernel_launch(void* const* d_in, const int* in_sizes, int n_in,
                              void* d_out, int out_size, void* d_ws, size_t ws_size,
                              hipStream_t stream) {
    const float* qp    = (const float*)d_in[0];
    const float* feat  = (const float*)d_in[1];
    const int*   table = (const int*)d_in[2];
    float*       out   = (float*)d_out;

    const int M = in_sizes[0] / 3;

    // Workspace: hist8[NXCD*NBINS+2] (16B-pad) | list[NBINS] | ovf[M] | sq8
    const size_t histB = ((NXCD * NBINS + 2) * sizeof(int) + 15) & ~(size_t)15;
    const size_t listB = (NBINS * sizeof(int) + 15) & ~(size_t)15;
    int* hist8 = (int*)d_ws;
    int* nact  = hist8 + NXCD * NBINS + 1;
    int* list  = (int*)((char*)d_ws + histB);
    f4*  ovf   = (f4*)((char*)d_ws + histB + listB);
    f4*  sq8   = ovf + M;

    const size_t fixed = histB + listB + (size_t)M * 16;
    size_t cap = (ws_size > fixed)
               ? (ws_size - fixed) / ((size_t)NXCD * NBINS * 16) : 0;
    int Cr = (cap > C8) ? C8 : (int)cap;
    if (Cr < 1) Cr = 1;

    const int block = 256;
    zero_kernel<<<(NXCD * NBINS + 2 + block - 1) / block, block, 0, stream>>>(hist8);
    bin_kernel<<<(M + block - 1) / block, block, 0, stream>>>(qp, hist8, sq8, ovf, Cr, M);
    compact_kernel<<<(NBINS + block - 1) / block, block, 0, stream>>>(hist8, nact, list);
    voxel_trilinear_kernel<<<2048, 256, 0, stream>>>(sq8, feat, table, hist8,
                                                     nact, list, out, Cr);
    ovf_kernel<<<512, 256, 0, stream>>>(ovf, hist8, feat, table, out, M);
}

// Round 14
// 234.549 us; speedup vs baseline: 1.1143x; 1.1143x over previous
//
#include <hip/hip_runtime.h>

// VoxelHashTableFlowTraverse: 8-corner hash-grid lookup + trilinear blend.
// R14 = R10 geometry (4x4x2 bins, 512thr, f32 rows, 16-lane blend) +
// software-pipelined staging: persistent blocks walk a compacted active-bin
// list; while blending bin b, each thread prefetches bin b+stride fully into
// REGISTERS (per-chunk redundant hash -> table -> feat chain, no barriers in
// the prefetch path; counts via broadcast loads; query slot into a reg).
// Loop top: barrier, ds_write regs, barrier, blend. The 2-3 dependent
// global-load rounds per bin (the measured ~100us serialization residue)
// hide under the previous bin's blend.

#define TABLE_MASK ((1u << 20) - 1u)
#define FEAT_DIM 120
#define ROW_STRIDE 120            // floats per row == NCHUNK*4 (contiguous)
#define NROWS 75                  // 5 x 5 x 3 neighborhood rows
#define NCHUNK 30                 // 120 floats = 30 float4 per row
#define TOTCH (NROWS * NCHUNK)    // 2250 chunks per bin
#define NSLOT 5                   // ceil(2250 / 512)
#define NXCD 8
#define C8 32                     // per-XCD per-bin capacity (mean ~14)

// Bins: 4x4x2 voxels -> 32 x 64 x 16 = 32768 bins.
#define NBINS_X 32
#define NBINS_Y 64
#define NBINS_Z 16
#define NBINS (NBINS_X * NBINS_Y * NBINS_Z)

typedef float f4 __attribute__((ext_vector_type(4)));

__global__ __launch_bounds__(256) void zero_kernel(int* __restrict__ hist8) {
    const int i = blockIdx.x * blockDim.x + threadIdx.x;
    if (i < NXCD * NBINS + 2) hist8[i] = 0;  // +0: ovf count, +1: active count
}

// Single-pass binning with XCD-local counters (RMW at the issuing XCD's L2).
// Stores pre-divided grid coords {gx,gy,gz,bits(q)}.
__global__ __launch_bounds__(256) void bin_kernel(
    const float* __restrict__ qp, int* __restrict__ hist8,
    f4* __restrict__ sq8, f4* __restrict__ ovf, int Cr, int M)
{
    const int q = blockIdx.x * blockDim.x + threadIdx.x;
    if (q >= M) return;

    int xcd;
    asm volatile("s_getreg_b32 %0, hwreg(HW_REG_XCC_ID)" : "=s"(xcd));
    xcd &= (NXCD - 1);

    // Divide by 0.1f (not *10) to match reference rounding.
    const float gx = qp[3 * q + 0] / 0.1f;
    const float gy = qp[3 * q + 1] / 0.1f;
    const float gz = qp[3 * q + 2] / 0.1f;
    const int bx = (int)floorf(gx);
    const int by = (int)floorf(gy);
    const int bz = (int)floorf(gz);
    const int kx = ((bx + 32) >> 2) & (NBINS_X - 1);
    const int ky = ((by + 96) >> 2) & (NBINS_Y - 1);
    const int kz = (bz >> 1) & (NBINS_Z - 1);
    const int key = ((kx * NBINS_Y) + ky) * NBINS_Z + kz;

    const int pos = __hip_atomic_fetch_add(&hist8[xcd * NBINS + key], 1,
                                           __ATOMIC_RELAXED,
                                           __HIP_MEMORY_SCOPE_WORKGROUP);
    f4 s;
    s.x = gx; s.y = gy; s.z = gz; s.w = __int_as_float(q);
    if (pos < Cr) {
        sq8[((size_t)xcd * NBINS + key) * C8 + pos] = s;
    } else {
        const int o = atomicAdd(&hist8[NXCD * NBINS], 1);   // device scope, rare
        if (o < M) ovf[o] = s;
    }
}

// Compact: append bins with any queries to the active list.
__global__ __launch_bounds__(256) void compact_kernel(
    const int* __restrict__ hist8, int* __restrict__ nact,
    int* __restrict__ list)
{
    const int i = blockIdx.x * blockDim.x + threadIdx.x;
    if (i >= NBINS) return;
    int tot = 0;
#pragma unroll
    for (int s = 0; s < NXCD; ++s) tot += hist8[s * NBINS + i];
    if (tot > 0) {
        const int p = atomicAdd(nact, 1);
        list[p] = i;
    }
}

// Main: persistent blocks, software-pipelined (prefetch bin b+stride into
// registers while blending bin b).
__global__ __launch_bounds__(512, 4) void voxel_trilinear_kernel(
    const f4*    __restrict__ sq8,     // [NXCD][NBINS][C8] padded bin slots
    const float* __restrict__ feat,    // [n_vox,120]
    const int*   __restrict__ table,   // [2^20]
    const int*   __restrict__ hist8,   // [NXCD][NBINS] bin counts
    const int*   __restrict__ nactp,   // active count
    const int*   __restrict__ list,    // active bin ids
    float*       __restrict__ out,     // [M,120]
    int Cr)
{
    __shared__ f4    sqL[NXCD * C8];            // 4 KB
    __shared__ float rows[NROWS * ROW_STRIDE];  // 36 KB

    const int t = threadIdx.x;
    const int nact = *nactp;
    const int stride = gridDim.x;

    if (blockIdx.x >= nact) return;

    // ---- prefetch state (registers) ----
    f4   rreg[NSLOT];
    f4   qreg;
    bool qok = false;
    int  qdst = 0;
    int  total = 0;

    auto prefetch = [&](int wg) {
        // Counts (8 broadcast loads; every thread needs total).
        int c[8];
#pragma unroll
        for (int i = 0; i < 8; ++i) {
            int v = hist8[i * NBINS + wg];
            c[i] = (v > Cr) ? Cr : v;     // overflow handled by ovf_kernel
        }
        total = 0;
#pragma unroll
        for (int i = 0; i < 8; ++i) total += c[i];

        // Query slot (t<256): segment seg, lane within segment.
        qok = false;
        if (t < 256) {
            const int seg = t >> 5, lane = t & 31;
            int p = 0;
#pragma unroll
            for (int i = 0; i < 8; ++i) p += (i < seg) ? c[i] : 0;
            if (lane < c[seg]) {
                qok = true;
                qdst = p + lane;
                qreg = sq8[((size_t)seg * NBINS + wg) * C8 + lane];
            }
        }

        // Rows: per-chunk redundant hash -> table -> feat chain (no LDS).
        const int binx = wg >> 10;
        const int biny = (wg >> 4) & 63;
        const int binz = wg & 15;
        const int vx0 = binx * 4 - 32;
        const int vy0 = biny * 4 - 96;
        const int vz0 = binz * 2;
#pragma unroll
        for (int s = 0; s < NSLOT; ++s) {
            const int idx = t + s * 512;
            f4 val = (f4)(0.0f);
            if (idx < TOTCH) {
                const int row = idx / NCHUNK;
                const int chunk = idx - row * NCHUNK;
                const int i = row / 15;          // x offset 0..4
                const int j = (row / 3) % 5;     // y offset 0..4
                const int k = row % 3;           // z offset 0..2
                const unsigned h = (unsigned)(vx0 + i) * 73856093u
                                 + (unsigned)(vy0 + j) * 19349669u
                                 + (unsigned)(vz0 + k) * 83492791u;
                const int v = table[h & TABLE_MASK];
                if (v >= 0)
                    val = *reinterpret_cast<const f4*>(
                        feat + (size_t)v * FEAT_DIM + chunk * 4);
            }
            rreg[s] = val;
        }
    };

    // Prologue: prefetch first bin.
    prefetch(list[blockIdx.x]);

    for (int bi = blockIdx.x; bi < nact; bi += stride) {
        __syncthreads();                 // previous blend done reading LDS

        // Stage prefetched registers into LDS.
#pragma unroll
        for (int s = 0; s < NSLOT; ++s) {
            const int idx = t + s * 512;
            if (idx < TOTCH)
                *reinterpret_cast<f4*>(rows + idx * 4) = rreg[s];
        }
        if (qok) sqL[qdst] = qreg;
        const int ct = total;            // save before prefetch overwrites
        __syncthreads();                 // staging visible

        // Prefetch next bin (loads fly under the blend below).
        const int nb = bi + stride;
        if (nb < nact) prefetch(list[nb]);

        // Blend: 16 lanes per query, 32 query-groups per block.
        const int group = t >> 4;
        const int l = t & 15;
        const int CX[8] = {0, 1, 0, 0, 1, 1, 0, 1};
        const int CY[8] = {0, 0, 1, 0, 1, 0, 1, 1};
        const int CZ[8] = {0, 0, 0, 1, 0, 1, 1, 1};

        for (int qs = group; qs < ct; qs += 32) {
            const f4 qv = sqL[qs];
            const float rx = qv.x - floorf(qv.x);
            const float ry = qv.y - floorf(qv.y);
            const float rz = qv.z - floorf(qv.z);
            const int q = __float_as_int(qv.w);
            const int lx = ((int)floorf(qv.x) + 32) & 3;
            const int ly = ((int)floorf(qv.y) + 96) & 3;
            const int lz = (int)floorf(qv.z) & 1;

            const float sx = 1.0f - rx, sy = 1.0f - ry, sz = 1.0f - rz;
            // Corner order matches reference.
            float w[8];
            w[0] = sx * sy * sz;
            w[1] = rx * sy * sz;
            w[2] = sx * ry * sz;
            w[3] = sx * sy * rz;
            w[4] = rx * ry * sz;
            w[5] = rx * sy * rz;
            w[6] = sx * ry * rz;
            w[7] = rx * ry * rz;

            f4 a0 = (f4)(0.0f), a1 = (f4)(0.0f);
#pragma unroll
            for (int k = 0; k < 8; ++k) {
                const int row = ((lx + CX[k]) * 5 + (ly + CY[k])) * 3 + (lz + CZ[k]);
                const float* rp = rows + row * ROW_STRIDE;
                const f4 fa = *reinterpret_cast<const f4*>(rp + l * 4);
                const f4 fb = *reinterpret_cast<const f4*>(rp + 56 + l * 4);
                a0 += fa * w[k];
                a1 += fb * w[k];
            }

            float* po = out + (size_t)q * FEAT_DIM;
            __builtin_nontemporal_store(a0, reinterpret_cast<f4*>(po + l * 4));
            if (l >= 2)
                __builtin_nontemporal_store(a1, reinterpret_cast<f4*>(po + 56 + l * 4));
        }
    }
}

// Overflow fixup: direct 16-lane gather per query (normally ~zero work).
__global__ __launch_bounds__(256) void ovf_kernel(
    const f4*    __restrict__ ovf,
    const int*   __restrict__ hist8,   // hist8[NXCD*NBINS] = ovf count
    const float* __restrict__ feat,
    const int*   __restrict__ table,
    float*       __restrict__ out,
    int M)
{
    int n = hist8[NXCD * NBINS];
    if (n > M) n = M;
    if (n == 0) return;

    const int nthreads = gridDim.x * 256;
    for (int i = blockIdx.x * 256 + threadIdx.x; i < n * 16; i += nthreads) {
        const int g = i >> 4;
        const int l = i & 15;
        const f4 qv = ovf[g];
        const float gx = qv.x, gy = qv.y, gz = qv.z;
        const int q = __float_as_int(qv.w);
        const float flx = floorf(gx), fly = floorf(gy), flz = floorf(gz);
        const float rx = gx - flx, ry = gy - fly, rz = gz - flz;
        const int bx = (int)flx, by = (int)fly, bz = (int)flz;

        const unsigned hx0 = (unsigned)bx * 73856093u;
        const unsigned hy0 = (unsigned)by * 19349669u;
        const unsigned hz0 = (unsigned)bz * 83492791u;
        const unsigned hx1 = hx0 + 73856093u;
        const unsigned hy1 = hy0 + 19349669u;
        const unsigned hz1 = hz0 + 83492791u;

        unsigned h[8];
        h[0] = (hx0 + hy0 + hz0) & TABLE_MASK;
        h[1] = (hx1 + hy0 + hz0) & TABLE_MASK;
        h[2] = (hx0 + hy1 + hz0) & TABLE_MASK;
        h[3] = (hx0 + hy0 + hz1) & TABLE_MASK;
        h[4] = (hx1 + hy1 + hz0) & TABLE_MASK;
        h[5] = (hx1 + hy0 + hz1) & TABLE_MASK;
        h[6] = (hx0 + hy1 + hz1) & TABLE_MASK;
        h[7] = (hx1 + hy1 + hz1) & TABLE_MASK;

        int vidx[8];
#pragma unroll
        for (int k = 0; k < 8; ++k) vidx[k] = table[h[k]];

        const float sxw = 1.0f - rx, syw = 1.0f - ry, szw = 1.0f - rz;
        float w[8];
        w[0] = sxw * syw * szw;
        w[1] = rx  * syw * szw;
        w[2] = sxw * ry  * szw;
        w[3] = sxw * syw * rz;
        w[4] = rx  * ry  * szw;
        w[5] = rx  * syw * rz;
        w[6] = sxw * ry  * rz;
        w[7] = rx  * ry  * rz;

        f4 a0 = (f4)(0.0f), a1 = (f4)(0.0f);
#pragma unroll
        for (int k = 0; k < 8; ++k) {
            const int v = vidx[k] >= 0 ? vidx[k] : 0;
            const float wk = vidx[k] >= 0 ? w[k] : 0.0f;
            const float* rp = feat + (size_t)v * FEAT_DIM;
            const f4 fa = *reinterpret_cast<const f4*>(rp + l * 4);
            const f4 fb = *reinterpret_cast<const f4*>(rp + 56 + l * 4);
            a0 += fa * wk;
            a1 += fb * wk;
        }

        float* po = out + (size_t)q * FEAT_DIM;
        __builtin_nontemporal_store(a0, reinterpret_cast<f4*>(po + l * 4));
        if (l >= 2)
            __builtin_nontemporal_store(a1, reinterpret_cast<f4*>(po + 56 + l * 4));
    }
}

extern "C" void kernel_launch(void* const* d_in, const int* in_sizes, int n_in,
                              void* d_out, int out_size, void* d_ws, size_t ws_size,
                              hipStream_t stream) {
    const float* qp    = (const float*)d_in[0];
    const float* feat  = (const float*)d_in[1];
    const int*   table = (const int*)d_in[2];
    float*       out   = (float*)d_out;

    const int M = in_sizes[0] / 3;

    // Workspace: hist8[NXCD*NBINS+2] (16B-pad) | list[NBINS] | ovf[M] | sq8
    const size_t histB = ((NXCD * NBINS + 2) * sizeof(int) + 15) & ~(size_t)15;
    const size_t listB = (NBINS * sizeof(int) + 15) & ~(size_t)15;
    int* hist8 = (int*)d_ws;
    int* nact  = hist8 + NXCD * NBINS + 1;
    int* list  = (int*)((char*)d_ws + histB);
    f4*  ovf   = (f4*)((char*)d_ws + histB + listB);
    f4*  sq8   = ovf + M;

    const size_t fixed = histB + listB + (size_t)M * 16;
    size_t cap = (ws_size > fixed)
               ? (ws_size - fixed) / ((size_t)NXCD * NBINS * 16) : 0;
    int Cr = (cap > C8) ? C8 : (int)cap;
    if (Cr < 1) Cr = 1;

    const int block = 256;
    zero_kernel<<<(NXCD * NBINS + 2 + block - 1) / block, block, 0, stream>>>(hist8);
    bin_kernel<<<(M + block - 1) / block, block, 0, stream>>>(qp, hist8, sq8, ovf, Cr, M);
    compact_kernel<<<(NBINS + block - 1) / block, block, 0, stream>>>(hist8, nact, list);
    voxel_trilinear_kernel<<<1024, 512, 0, stream>>>(sq8, feat, table, hist8,
                                                     nact, list, out, Cr);
    ovf_kernel<<<512, 256, 0, stream>>>(ovf, hist8, feat, table, out, M);
}